// Round 1
// baseline (21700.858 us; speedup 1.0000x reference)
//
#include <hip/hip_runtime.h>
#include <hip/hip_bf16.h>
#include <math.h>

#define N_NODES 50000
#define N_EDGES 800000
#define N_GRAPHS 1024
#define HD 128
#define NLAYERS 5
#define EDGE_IN 41
#define NT 3
#define LN_EPS 1e-5f

__device__ __forceinline__ float silu_f(float v) { return v / (1.0f + __expf(-v)); }

// ---------------- zero ----------------
__global__ void k_zero(float* __restrict__ p, int n) {
    int i = blockIdx.x * 256 + threadIdx.x;
    if (i < n) p[i] = 0.0f;
}

// ---------------- node embed: x = silu(LN(atom @ emb_w + emb_b)) ----------------
__global__ __launch_bounds__(128) void k_node_embed(
    const float* __restrict__ atom, const float* __restrict__ w,
    const float* __restrict__ b, const float* __restrict__ g,
    const float* __restrict__ bet, float* __restrict__ x)
{
    int node = blockIdx.x;
    int h = threadIdx.x;
    float4 a = *(const float4*)(atom + (size_t)node * 4);
    float acc = b[h] + a.x * w[h] + a.y * w[HD + h] + a.z * w[2 * HD + h] + a.w * w[3 * HD + h];
    // LN over 128 channels (2 waves)
    __shared__ float s1[2], s2[2];
    float sum = acc, sq = acc * acc;
    for (int off = 32; off > 0; off >>= 1) { sum += __shfl_down(sum, off); sq += __shfl_down(sq, off); }
    int wid = h >> 6, lane = h & 63;
    if (lane == 0) { s1[wid] = sum; s2[wid] = sq; }
    __syncthreads();
    float m = (s1[0] + s1[1]) * (1.0f / 128.0f);
    float v = (s2[0] + s2[1]) * (1.0f / 128.0f) - m * m;
    float y = (acc - m) * rsqrtf(v + LN_EPS) * g[h] + bet[h];
    x[(size_t)node * HD + h] = silu_f(y);
}

// ---------------- edge embed: e = silu(nbr_fea @ edge_w + edge_b) ----------------
#define ETILE 32
__global__ __launch_bounds__(128) void k_edge_embed(
    const float* __restrict__ fea, const float* __restrict__ w,
    const float* __restrict__ b, float* __restrict__ e)
{
    __shared__ float sf[ETILE][EDGE_IN + 1];
    int e0 = blockIdx.x * ETILE;
    int tid = threadIdx.x;
    for (int i = tid; i < ETILE * EDGE_IN; i += 128) {
        int m = i / EDGE_IN, k = i % EDGE_IN;
        sf[m][k] = fea[(size_t)(e0 + m) * EDGE_IN + k];
    }
    __syncthreads();
    float bb = b[tid];
    float acc[ETILE];
#pragma unroll
    for (int m = 0; m < ETILE; m++) acc[m] = bb;
    for (int k = 0; k < EDGE_IN; k++) {
        float wk = w[k * HD + tid];
#pragma unroll
        for (int m = 0; m < ETILE; m++) acc[m] += sf[m][k] * wk;
    }
#pragma unroll
    for (int m = 0; m < ETILE; m++)
        e[(size_t)(e0 + m) * HD + tid] = silu_f(acc[m]);
}

// ---------------- degree count (over edges, dst) ----------------
__global__ void k_count(const int* __restrict__ nbr_idx, float* __restrict__ cnt) {
    int i = blockIdx.x * 256 + threadIdx.x;
    if (i < N_EDGES) atomicAdd(&cnt[nbr_idx[2 * i + 1]], 1.0f);
}

// ---------------- graph count (over nodes) ----------------
__global__ void k_gcount(const int* __restrict__ bm, float* __restrict__ gcnt) {
    int i = blockIdx.x * 256 + threadIdx.x;
    if (i < N_NODES) atomicAdd(&gcnt[bm[i]], 1.0f);
}

// ---------------- fused conv layer ----------------
// m1 = silu(concat(x[src], e) @ W1 + b1)  [32 x 256]   (kept in LDS, transposed)
// m2 = silu(m1 @ W2 + b2)                [32 x 128]
// atomicAdd into aggr[dst]
#define TM 32
#define PITCH_A 36

#define MAC4(a, s, wv) { (a).x += (s)*(wv).x; (a).y += (s)*(wv).y; (a).z += (s)*(wv).z; (a).w += (s)*(wv).w; }

__global__ __launch_bounds__(256) void k_conv(
    const float* __restrict__ x, const float* __restrict__ e,
    const int* __restrict__ nbr_idx,
    const float* __restrict__ w1, const float* __restrict__ b1,
    const float* __restrict__ w2, const float* __restrict__ b2,
    float* __restrict__ aggr)
{
    __shared__ float sAT[64][PITCH_A];     // A^T staging: [k][m]
    __shared__ float sW[64][128];          // weight tile
    __shared__ float sM1T[256][PITCH_A];   // m1^T: [k][m]
    __shared__ int s_src[TM], s_dst[TM];

    int tid = threadIdx.x;
    int e0 = blockIdx.x * TM;
    if (tid < TM) {
        s_src[tid] = nbr_idx[2 * (e0 + tid)];
        s_dst[tid] = nbr_idx[2 * (e0 + tid) + 1];
    }
    __syncthreads();

    int m0 = (tid >> 5) * 4;   // row base 0..28
    int c0 = (tid & 31) * 4;   // col base 0..124

    int a_row = tid >> 3;          // 0..31 (edge index for staging)
    int a_kb = (tid & 7) * 8;      // 0..56

    // ---------- phase 1 ----------
    for (int nch = 0; nch < 2; ++nch) {
        int n0 = nch * 128;
        float4 acc[4] = {};
        for (int k0 = 0; k0 < 256; k0 += 64) {
            __syncthreads();
            // stage A^T tile
            {
                int kg = k0 + a_kb;
                const float* sp;
                if (kg < 128) sp = x + (size_t)s_src[a_row] * HD + kg;
                else          sp = e + (size_t)(e0 + a_row) * HD + (kg - 128);
                float4 v0 = *(const float4*)(sp);
                float4 v1 = *(const float4*)(sp + 4);
                sAT[a_kb + 0][a_row] = v0.x; sAT[a_kb + 1][a_row] = v0.y;
                sAT[a_kb + 2][a_row] = v0.z; sAT[a_kb + 3][a_row] = v0.w;
                sAT[a_kb + 4][a_row] = v1.x; sAT[a_kb + 5][a_row] = v1.y;
                sAT[a_kb + 6][a_row] = v1.z; sAT[a_kb + 7][a_row] = v1.w;
            }
            // stage W1 tile [64 x 128]
#pragma unroll
            for (int j = 0; j < 8; ++j) {
                int lin = tid + j * 256;
                int kk = lin >> 5;
                int cc = (lin & 31) * 4;
                *(float4*)&sW[kk][cc] = *(const float4*)(w1 + (size_t)(k0 + kk) * 256 + n0 + cc);
            }
            __syncthreads();
#pragma unroll 16
            for (int kk = 0; kk < 64; ++kk) {
                float4 av = *(const float4*)&sAT[kk][m0];
                float4 wv = *(const float4*)&sW[kk][c0];
                MAC4(acc[0], av.x, wv);
                MAC4(acc[1], av.y, wv);
                MAC4(acc[2], av.z, wv);
                MAC4(acc[3], av.w, wv);
            }
        }
        // epilogue: bias + silu -> sM1T (no race: sM1T untouched above)
#pragma unroll
        for (int r = 0; r < 4; r++) {
            float4 a = acc[r];
            int col = n0 + c0;
            sM1T[col + 0][m0 + r] = silu_f(a.x + b1[col + 0]);
            sM1T[col + 1][m0 + r] = silu_f(a.y + b1[col + 1]);
            sM1T[col + 2][m0 + r] = silu_f(a.z + b1[col + 2]);
            sM1T[col + 3][m0 + r] = silu_f(a.w + b1[col + 3]);
        }
    }
    __syncthreads();

    // ---------- phase 2 ----------
    float4 acc2[4] = {};
    for (int k0 = 0; k0 < 256; k0 += 64) {
        __syncthreads();
#pragma unroll
        for (int j = 0; j < 8; ++j) {
            int lin = tid + j * 256;
            int kk = lin >> 5;
            int cc = (lin & 31) * 4;
            *(float4*)&sW[kk][cc] = *(const float4*)(w2 + (size_t)(k0 + kk) * 128 + cc);
        }
        __syncthreads();
#pragma unroll 16
        for (int kk = 0; kk < 64; ++kk) {
            float4 av = *(const float4*)&sM1T[k0 + kk][m0];
            float4 wv = *(const float4*)&sW[kk][c0];
            MAC4(acc2[0], av.x, wv);
            MAC4(acc2[1], av.y, wv);
            MAC4(acc2[2], av.z, wv);
            MAC4(acc2[3], av.w, wv);
        }
    }
    // epilogue: bias + silu + atomic scatter
    float b2v0 = b2[c0], b2v1 = b2[c0 + 1], b2v2 = b2[c0 + 2], b2v3 = b2[c0 + 3];
#pragma unroll
    for (int r = 0; r < 4; r++) {
        int dst = s_dst[m0 + r];
        float* base = aggr + (size_t)dst * HD + c0;
        atomicAdd(base + 0, silu_f(acc2[r].x + b2v0));
        atomicAdd(base + 1, silu_f(acc2[r].y + b2v1));
        atomicAdd(base + 2, silu_f(acc2[r].z + b2v2));
        atomicAdd(base + 3, silu_f(acc2[r].w + b2v3));
    }
}

// ---------------- post: x = LN(x + aggr/cnt) ----------------
__global__ __launch_bounds__(128) void k_post(
    const float* __restrict__ aggr, const float* __restrict__ cnt,
    const float* __restrict__ g, const float* __restrict__ bet,
    float* __restrict__ x)
{
    int node = blockIdx.x;
    int h = threadIdx.x;
    float inv = 1.0f / fmaxf(cnt[node], 1.0f);
    float acc = x[(size_t)node * HD + h] + aggr[(size_t)node * HD + h] * inv;
    __shared__ float s1[2], s2[2];
    float sum = acc, sq = acc * acc;
    for (int off = 32; off > 0; off >>= 1) { sum += __shfl_down(sum, off); sq += __shfl_down(sq, off); }
    int wid = h >> 6, lane = h & 63;
    if (lane == 0) { s1[wid] = sum; s2[wid] = sq; }
    __syncthreads();
    float m = (s1[0] + s1[1]) * (1.0f / 128.0f);
    float v = (s2[0] + s2[1]) * (1.0f / 128.0f) - m * m;
    x[(size_t)node * HD + h] = (acc - m) * rsqrtf(v + LN_EPS) * g[h] + bet[h];
}

// ---------------- graph pooling: crystal += x[node] ----------------
__global__ __launch_bounds__(128) void k_gaggr(
    const float* __restrict__ x, const int* __restrict__ bm,
    float* __restrict__ crystal)
{
    int node = blockIdx.x;
    int h = threadIdx.x;
    atomicAdd(&crystal[(size_t)bm[node] * HD + h], x[(size_t)node * HD + h]);
}

// ---------------- readout MLP ----------------
__global__ __launch_bounds__(128) void k_readout(
    const float* __restrict__ crystal, const float* __restrict__ gcnt,
    const float* __restrict__ w1, const float* __restrict__ b1,
    const float* __restrict__ w2, const float* __restrict__ b2,
    const float* __restrict__ w3, const float* __restrict__ b3,
    float* __restrict__ out)
{
    int gph = blockIdx.x;
    int t = threadIdx.x;
    __shared__ float sc[HD], sh1[HD], sh2[64];
    float inv = 1.0f / fmaxf(gcnt[gph], 1.0f);
    sc[t] = crystal[(size_t)gph * HD + t] * inv;
    __syncthreads();
    float acc = b1[t];
    for (int k = 0; k < HD; k++) acc += sc[k] * w1[k * HD + t];
    sh1[t] = silu_f(acc);
    __syncthreads();
    if (t < 64) {
        float a2 = b2[t];
        for (int k = 0; k < HD; k++) a2 += sh1[k] * w2[k * 64 + t];
        sh2[t] = silu_f(a2);
    }
    __syncthreads();
    if (t < NT) {
        float a3 = b3[t];
        for (int k = 0; k < 64; k++) a3 += sh2[k] * w3[k * NT + t];
        out[(size_t)gph * NT + t] = a3;
    }
}

extern "C" void kernel_launch(void* const* d_in, const int* in_sizes, int n_in,
                              void* d_out, int out_size, void* d_ws, size_t ws_size,
                              hipStream_t stream)
{
    const float* atom_fea = (const float*)d_in[0];
    const float* nbr_fea  = (const float*)d_in[1];
    const int*   nbr_idx  = (const int*)d_in[2];
    const int*   bm       = (const int*)d_in[3];
    const float* emb_w    = (const float*)d_in[4];
    const float* emb_b    = (const float*)d_in[5];
    const float* emb_ln_g = (const float*)d_in[6];
    const float* emb_ln_b = (const float*)d_in[7];
    const float* edge_w   = (const float*)d_in[8];
    const float* edge_b   = (const float*)d_in[9];
    const float* conv_w1  = (const float*)d_in[10];
    const float* conv_b1  = (const float*)d_in[11];
    const float* conv_w2  = (const float*)d_in[12];
    const float* conv_b2  = (const float*)d_in[13];
    const float* ln_g     = (const float*)d_in[14];
    const float* ln_b     = (const float*)d_in[15];
    const float* out_w1   = (const float*)d_in[16];
    const float* out_b1   = (const float*)d_in[17];
    const float* out_w2   = (const float*)d_in[18];
    const float* out_b2   = (const float*)d_in[19];
    const float* out_w3   = (const float*)d_in[20];
    const float* out_b3   = (const float*)d_in[21];
    float* out = (float*)d_out;

    // workspace layout (floats)
    float* xbuf    = (float*)d_ws;                 // 50000*128
    float* ebuf    = xbuf + (size_t)N_NODES * HD;  // 800000*128
    float* aggr    = ebuf + (size_t)N_EDGES * HD;  // 50000*128
    float* cnt     = aggr + (size_t)N_NODES * HD;  // 50000
    float* crystal = cnt + N_NODES;                // 1024*128
    float* gcnt    = crystal + N_GRAPHS * HD;      // 1024

    // zero cnt + crystal + gcnt (contiguous)
    int zn = N_NODES + N_GRAPHS * HD + N_GRAPHS;
    k_zero<<<(zn + 255) / 256, 256, 0, stream>>>(cnt, zn);

    k_node_embed<<<N_NODES, 128, 0, stream>>>(atom_fea, emb_w, emb_b, emb_ln_g, emb_ln_b, xbuf);
    k_edge_embed<<<N_EDGES / ETILE, 128, 0, stream>>>(nbr_fea, edge_w, edge_b, ebuf);
    k_count<<<N_EDGES / 256, 256, 0, stream>>>(nbr_idx, cnt);
    k_gcount<<<(N_NODES + 255) / 256, 256, 0, stream>>>(bm, gcnt);

    for (int l = 0; l < NLAYERS; ++l) {
        k_zero<<<(N_NODES * HD) / 256, 256, 0, stream>>>(aggr, N_NODES * HD);
        k_conv<<<N_EDGES / TM, 256, 0, stream>>>(
            xbuf, ebuf, nbr_idx,
            conv_w1 + (size_t)l * 256 * 256, conv_b1 + (size_t)l * 256,
            conv_w2 + (size_t)l * 256 * 128, conv_b2 + (size_t)l * 128,
            aggr);
        k_post<<<N_NODES, 128, 0, stream>>>(aggr, cnt, ln_g + (size_t)l * HD, ln_b + (size_t)l * HD, xbuf);
    }

    k_gaggr<<<N_NODES, 128, 0, stream>>>(xbuf, bm, crystal);
    k_readout<<<N_GRAPHS, 128, 0, stream>>>(crystal, gcnt, out_w1, out_b1, out_w2, out_b2, out_w3, out_b3, out);
}

// Round 2
// 3926.783 us; speedup vs baseline: 5.5264x; 5.5264x over previous
//
#include <hip/hip_runtime.h>
#include <hip/hip_bf16.h>
#include <math.h>

#define N_NODES 50000
#define N_EDGES 800000
#define N_GRAPHS 1024
#define HD 128
#define NLAYERS 5
#define EDGE_IN 41
#define NT 3
#define LN_EPS 1e-5f

typedef unsigned int uint;
typedef unsigned short ushort;
typedef __attribute__((ext_vector_type(8))) short short8;
typedef __attribute__((ext_vector_type(16))) float f32x16;

__device__ __forceinline__ float silu_f(float v) { return v / (1.0f + __expf(-v)); }

// round-to-nearest-even f32 -> bf16 bits
__device__ __forceinline__ ushort f2bf(float f) {
    uint u = __float_as_uint(f);
    u = u + 0x7FFFu + ((u >> 16) & 1u);
    return (ushort)(u >> 16);
}
// pack two f32 into bf16x2 (lo,hi)
__device__ __forceinline__ uint pk2(float lo, float hi) {
    uint a = __float_as_uint(lo);
    uint b = __float_as_uint(hi);
    a = (a + 0x7FFFu + ((a >> 16) & 1u)) >> 16;
    b = (b + 0x7FFFu + ((b >> 16) & 1u)) & 0xFFFF0000u;
    return b | a;
}

__device__ __forceinline__ short8 ld16(const ushort* p) {
    union { int4 i; short8 s; } u;
    u.i = *(const int4*)p;
    return u.s;
}

__device__ __forceinline__ f32x16 mfma32(short8 a, short8 b, f32x16 c) {
    return __builtin_amdgcn_mfma_f32_32x32x16_bf16(a, b, c, 0, 0, 0);
}

// ---------------- zero ----------------
__global__ void k_zero(float* __restrict__ p, int n) {
    int i = blockIdx.x * 256 + threadIdx.x;
    if (i < n) p[i] = 0.0f;
}

// ---------------- weight swizzle: B-fragment order for 32x32x16 bf16 ----------------
// frag (s,t): lane L, elem j  <-  W[k = s*16 + (L>>5)*8 + j][n = t*32 + (L&31)]
__global__ void k_swz_w1(const float* __restrict__ w1, ushort* __restrict__ w1s) {
    int i = blockIdx.x * 256 + threadIdx.x;            // 5 * 65536
    int l = i >> 16;
    int r = i & 65535;
    int j = r & 7, L = (r >> 3) & 63, t = (r >> 9) & 7, s = (r >> 12) & 15;
    int k = s * 16 + (L >> 5) * 8 + j;
    int n = t * 32 + (L & 31);
    w1s[i] = f2bf(w1[(size_t)l * 65536 + k * 256 + n]);
}
__global__ void k_swz_w2(const float* __restrict__ w2, ushort* __restrict__ w2s) {
    int i = blockIdx.x * 256 + threadIdx.x;            // 5 * 32768
    int l = i >> 15;
    int r = i & 32767;
    int j = r & 7, L = (r >> 3) & 63, t = (r >> 9) & 3, s = (r >> 11) & 15;
    int k = s * 16 + (L >> 5) * 8 + j;
    int n = t * 32 + (L & 31);
    w2s[i] = f2bf(w2[(size_t)l * 32768 + k * 128 + n]);
}

// ---------------- node embed: x = silu(LN(atom @ emb_w + emb_b)) ----------------
__global__ __launch_bounds__(128) void k_node_embed(
    const float* __restrict__ atom, const float* __restrict__ w,
    const float* __restrict__ b, const float* __restrict__ g,
    const float* __restrict__ bet, float* __restrict__ x, ushort* __restrict__ x_bf)
{
    int node = blockIdx.x;
    int h = threadIdx.x;
    float4 a = *(const float4*)(atom + (size_t)node * 4);
    float acc = b[h] + a.x * w[h] + a.y * w[HD + h] + a.z * w[2 * HD + h] + a.w * w[3 * HD + h];
    __shared__ float s1[2], s2[2];
    float sum = acc, sq = acc * acc;
    for (int off = 32; off > 0; off >>= 1) { sum += __shfl_down(sum, off); sq += __shfl_down(sq, off); }
    int wid = h >> 6, lane = h & 63;
    if (lane == 0) { s1[wid] = sum; s2[wid] = sq; }
    __syncthreads();
    float m = (s1[0] + s1[1]) * (1.0f / 128.0f);
    float v = (s2[0] + s2[1]) * (1.0f / 128.0f) - m * m;
    float y = (acc - m) * rsqrtf(v + LN_EPS) * g[h] + bet[h];
    y = silu_f(y);
    x[(size_t)node * HD + h] = y;
    x_bf[(size_t)node * HD + h] = f2bf(y);
}

// ---------------- edge embed -> bf16: e = silu(nbr_fea @ edge_w + edge_b) ----------------
#define ETILE 32
__global__ __launch_bounds__(128) void k_edge_embed(
    const float* __restrict__ fea, const float* __restrict__ w,
    const float* __restrict__ b, ushort* __restrict__ e_bf)
{
    __shared__ float sf[ETILE][EDGE_IN + 1];
    int e0 = blockIdx.x * ETILE;
    int tid = threadIdx.x;
    for (int i = tid; i < ETILE * EDGE_IN; i += 128) {
        int m = i / EDGE_IN, k = i % EDGE_IN;
        sf[m][k] = fea[(size_t)(e0 + m) * EDGE_IN + k];
    }
    __syncthreads();
    float bb = b[tid];
    float acc[ETILE];
#pragma unroll
    for (int m = 0; m < ETILE; m++) acc[m] = bb;
    for (int k = 0; k < EDGE_IN; k++) {
        float wk = w[k * HD + tid];
#pragma unroll
        for (int m = 0; m < ETILE; m++) acc[m] += sf[m][k] * wk;
    }
#pragma unroll
    for (int m = 0; m < ETILE; m++)
        e_bf[(size_t)(e0 + m) * HD + tid] = f2bf(silu_f(acc[m]));
}

// ---------------- degree / graph counts ----------------
__global__ void k_count(const int* __restrict__ nbr_idx, float* __restrict__ cnt) {
    int i = blockIdx.x * 256 + threadIdx.x;
    if (i < N_EDGES) atomicAdd(&cnt[nbr_idx[2 * i + 1]], 1.0f);
}
__global__ void k_gcount(const int* __restrict__ bm, float* __restrict__ gcnt) {
    int i = blockIdx.x * 256 + threadIdx.x;
    if (i < N_NODES) atomicAdd(&gcnt[bm[i]], 1.0f);
}

// ---------------- fused conv layer (MFMA bf16) ----------------
// block = 256 thr = 4 waves; each wave owns 32 edges.
// GEMM1: m1[32x256] = silu(concat(x[src],e) @ W1 + b1), in 4 n-chunks of 64
// GEMM2: m2[32x128] = silu(m1 @ W2 + b2), k accumulated chunk-by-chunk
// scatter: atomicAdd(aggr[dst])
#define M1PITCH 68
__global__ __launch_bounds__(256) void k_conv_mfma(
    const ushort* __restrict__ x_bf, const ushort* __restrict__ e_bf,
    const int* __restrict__ nbr_idx,
    const ushort* __restrict__ w1s, const float* __restrict__ b1,
    const ushort* __restrict__ w2s, const float* __restrict__ b2,
    float* __restrict__ aggr)
{
    __shared__ float sM1[4][32 * M1PITCH];   // per-wave m1 chunk [row][k], pitch 68
    __shared__ int sDst[128];

    int tid = threadIdx.x;
    int wv = tid >> 6;
    int L = tid & 63;
    int l31 = L & 31;
    int lhi = L >> 5;
    int eb = blockIdx.x * 128;
    int e0w = eb + wv * 32;

    if (tid < 128) sDst[tid] = nbr_idx[2 * (eb + tid) + 1];
    __syncthreads();

    int srcRow = nbr_idx[2 * (e0w + l31)];
    const ushort* xb = x_bf + (size_t)srcRow * HD + lhi * 8;
    const ushort* ep = e_bf + (size_t)(e0w + l31) * HD + lhi * 8;
    float* myM1 = sM1[wv];

    f32x16 acc2[4];
#pragma unroll
    for (int t = 0; t < 4; ++t)
#pragma unroll
        for (int i = 0; i < 16; ++i) acc2[t][i] = 0.0f;

    for (int c = 0; c < 4; ++c) {
        f32x16 acc1[2];
#pragma unroll
        for (int u = 0; u < 2; ++u)
#pragma unroll
            for (int i = 0; i < 16; ++i) acc1[u][i] = 0.0f;

        // GEMM1: k-steps 0..7 read x[src], 8..15 read e
#pragma unroll 4
        for (int s = 0; s < 8; ++s) {
            short8 a = ld16(xb + s * 16);
            short8 bb0 = ld16(w1s + (((s * 8 + 2 * c + 0) * 64 + L) << 3));
            short8 bb1 = ld16(w1s + (((s * 8 + 2 * c + 1) * 64 + L) << 3));
            acc1[0] = mfma32(a, bb0, acc1[0]);
            acc1[1] = mfma32(a, bb1, acc1[1]);
        }
#pragma unroll 4
        for (int s = 0; s < 8; ++s) {
            int sg = s + 8;
            short8 a = ld16(ep + s * 16);
            short8 bb0 = ld16(w1s + (((sg * 8 + 2 * c + 0) * 64 + L) << 3));
            short8 bb1 = ld16(w1s + (((sg * 8 + 2 * c + 1) * 64 + L) << 3));
            acc1[0] = mfma32(a, bb0, acc1[0]);
            acc1[1] = mfma32(a, bb1, acc1[1]);
        }

        // bias + silu -> sM1 (C layout: row=(r&3)+8*(r>>2)+4*lhi, col=u*32+l31)
        float bv0 = b1[c * 64 + l31];
        float bv1 = b1[c * 64 + 32 + l31];
#pragma unroll
        for (int u = 0; u < 2; ++u) {
            float bv = u ? bv1 : bv0;
#pragma unroll
            for (int r = 0; r < 16; ++r) {
                int row = (r & 3) + ((r >> 2) << 3) + (lhi << 2);
                myM1[row * M1PITCH + u * 32 + l31] = silu_f(acc1[u][r] + bv);
            }
        }

        // GEMM2 partial over this 64-k chunk
#pragma unroll
        for (int ss = 0; ss < 4; ++ss) {
            const float* ap = myM1 + l31 * M1PITCH + ss * 16 + lhi * 8;
            float4 f0 = *(const float4*)ap;
            float4 f1 = *(const float4*)(ap + 4);
            union { int4 i; short8 s; } a2;
            a2.i.x = pk2(f0.x, f0.y);
            a2.i.y = pk2(f0.z, f0.w);
            a2.i.z = pk2(f1.x, f1.y);
            a2.i.w = pk2(f1.z, f1.w);
            int sg = c * 4 + ss;
#pragma unroll
            for (int t = 0; t < 4; ++t) {
                short8 bb = ld16(w2s + (((sg * 4 + t) * 64 + L) << 3));
                acc2[t] = mfma32(a2.s, bb, acc2[t]);
            }
        }
    }

    // epilogue: bias + silu + coalesced atomic scatter
#pragma unroll
    for (int t = 0; t < 4; ++t) {
        float bv = b2[t * 32 + l31];
#pragma unroll
        for (int r = 0; r < 16; ++r) {
            int row = (r & 3) + ((r >> 2) << 3) + (lhi << 2);
            int dst = sDst[wv * 32 + row];
            float v = silu_f(acc2[t][r] + bv);
            atomicAdd(aggr + (size_t)dst * HD + t * 32 + l31, v);
        }
    }
}

// ---------------- post: x = LN(x + aggr/cnt); also emit bf16 ----------------
__global__ __launch_bounds__(128) void k_post(
    const float* __restrict__ aggr, const float* __restrict__ cnt,
    const float* __restrict__ g, const float* __restrict__ bet,
    float* __restrict__ x, ushort* __restrict__ x_bf)
{
    int node = blockIdx.x;
    int h = threadIdx.x;
    float inv = 1.0f / fmaxf(cnt[node], 1.0f);
    float acc = x[(size_t)node * HD + h] + aggr[(size_t)node * HD + h] * inv;
    __shared__ float s1[2], s2[2];
    float sum = acc, sq = acc * acc;
    for (int off = 32; off > 0; off >>= 1) { sum += __shfl_down(sum, off); sq += __shfl_down(sq, off); }
    int wid = h >> 6, lane = h & 63;
    if (lane == 0) { s1[wid] = sum; s2[wid] = sq; }
    __syncthreads();
    float m = (s1[0] + s1[1]) * (1.0f / 128.0f);
    float v = (s2[0] + s2[1]) * (1.0f / 128.0f) - m * m;
    float y = (acc - m) * rsqrtf(v + LN_EPS) * g[h] + bet[h];
    x[(size_t)node * HD + h] = y;
    x_bf[(size_t)node * HD + h] = f2bf(y);
}

// ---------------- graph pooling ----------------
__global__ __launch_bounds__(128) void k_gaggr(
    const float* __restrict__ x, const int* __restrict__ bm,
    float* __restrict__ crystal)
{
    int node = blockIdx.x;
    int h = threadIdx.x;
    atomicAdd(&crystal[(size_t)bm[node] * HD + h], x[(size_t)node * HD + h]);
}

// ---------------- readout MLP ----------------
__global__ __launch_bounds__(128) void k_readout(
    const float* __restrict__ crystal, const float* __restrict__ gcnt,
    const float* __restrict__ w1, const float* __restrict__ b1,
    const float* __restrict__ w2, const float* __restrict__ b2,
    const float* __restrict__ w3, const float* __restrict__ b3,
    float* __restrict__ out)
{
    int gph = blockIdx.x;
    int t = threadIdx.x;
    __shared__ float sc[HD], sh1[HD], sh2[64];
    float inv = 1.0f / fmaxf(gcnt[gph], 1.0f);
    sc[t] = crystal[(size_t)gph * HD + t] * inv;
    __syncthreads();
    float acc = b1[t];
    for (int k = 0; k < HD; k++) acc += sc[k] * w1[k * HD + t];
    sh1[t] = silu_f(acc);
    __syncthreads();
    if (t < 64) {
        float a2 = b2[t];
        for (int k = 0; k < HD; k++) a2 += sh1[k] * w2[k * 64 + t];
        sh2[t] = silu_f(a2);
    }
    __syncthreads();
    if (t < NT) {
        float a3 = b3[t];
        for (int k = 0; k < 64; k++) a3 += sh2[k] * w3[k * NT + t];
        out[(size_t)gph * NT + t] = a3;
    }
}

extern "C" void kernel_launch(void* const* d_in, const int* in_sizes, int n_in,
                              void* d_out, int out_size, void* d_ws, size_t ws_size,
                              hipStream_t stream)
{
    const float* atom_fea = (const float*)d_in[0];
    const float* nbr_fea  = (const float*)d_in[1];
    const int*   nbr_idx  = (const int*)d_in[2];
    const int*   bm       = (const int*)d_in[3];
    const float* emb_w    = (const float*)d_in[4];
    const float* emb_b    = (const float*)d_in[5];
    const float* emb_ln_g = (const float*)d_in[6];
    const float* emb_ln_b = (const float*)d_in[7];
    const float* edge_w   = (const float*)d_in[8];
    const float* edge_b   = (const float*)d_in[9];
    const float* conv_w1  = (const float*)d_in[10];
    const float* conv_b1  = (const float*)d_in[11];
    const float* conv_w2  = (const float*)d_in[12];
    const float* conv_b2  = (const float*)d_in[13];
    const float* ln_g     = (const float*)d_in[14];
    const float* ln_b     = (const float*)d_in[15];
    const float* out_w1   = (const float*)d_in[16];
    const float* out_b1   = (const float*)d_in[17];
    const float* out_w2   = (const float*)d_in[18];
    const float* out_b2   = (const float*)d_in[19];
    const float* out_w3   = (const float*)d_in[20];
    const float* out_b3   = (const float*)d_in[21];
    float* out = (float*)d_out;

    // ---- workspace layout (256B-aligned regions) ----
    char* base = (char*)d_ws;
    size_t off = 0;
    auto alloc = [&](size_t bytes) -> char* {
        char* p = base + off;
        off = (off + bytes + 255) & ~(size_t)255;
        return p;
    };
    float*  xbuf    = (float*) alloc((size_t)N_NODES * HD * 4);
    float*  aggr    = (float*) alloc((size_t)N_NODES * HD * 4);
    float*  cnt     = (float*) alloc((size_t)N_NODES * 4);
    float*  crystal = (float*) alloc((size_t)N_GRAPHS * HD * 4);
    float*  gcnt    = (float*) alloc((size_t)N_GRAPHS * 4);
    ushort* x_bf    = (ushort*)alloc((size_t)N_NODES * HD * 2);
    ushort* e_bf    = (ushort*)alloc((size_t)N_EDGES * HD * 2);
    ushort* w1s     = (ushort*)alloc((size_t)NLAYERS * 65536 * 2);
    ushort* w2s     = (ushort*)alloc((size_t)NLAYERS * 32768 * 2);

    // weights -> swizzled bf16
    k_swz_w1<<<(NLAYERS * 65536) / 256, 256, 0, stream>>>(conv_w1, w1s);
    k_swz_w2<<<(NLAYERS * 32768) / 256, 256, 0, stream>>>(conv_w2, w2s);

    // zero cnt + crystal + gcnt (contiguous region)
    int zn = N_NODES + N_GRAPHS * HD + N_GRAPHS + 128;  // covers padding gaps
    k_zero<<<(zn + 255) / 256, 256, 0, stream>>>(cnt, zn);

    k_node_embed<<<N_NODES, 128, 0, stream>>>(atom_fea, emb_w, emb_b, emb_ln_g, emb_ln_b, xbuf, x_bf);
    k_edge_embed<<<N_EDGES / ETILE, 128, 0, stream>>>(nbr_fea, edge_w, edge_b, e_bf);
    k_count<<<N_EDGES / 256, 256, 0, stream>>>(nbr_idx, cnt);
    k_gcount<<<(N_NODES + 255) / 256, 256, 0, stream>>>(bm, gcnt);

    for (int l = 0; l < NLAYERS; ++l) {
        k_zero<<<(N_NODES * HD) / 256, 256, 0, stream>>>(aggr, N_NODES * HD);
        k_conv_mfma<<<N_EDGES / 128, 256, 0, stream>>>(
            x_bf, e_bf, nbr_idx,
            w1s + (size_t)l * 65536, conv_b1 + (size_t)l * 256,
            w2s + (size_t)l * 32768, conv_b2 + (size_t)l * 128,
            aggr);
        k_post<<<N_NODES, 128, 0, stream>>>(aggr, cnt, ln_g + (size_t)l * HD, ln_b + (size_t)l * HD, xbuf, x_bf);
    }

    k_gaggr<<<N_NODES, 128, 0, stream>>>(xbuf, bm, crystal);
    k_readout<<<N_GRAPHS, 128, 0, stream>>>(crystal, gcnt, out_w1, out_b1, out_w2, out_b2, out_w3, out_b3, out);
}

// Round 3
// 3161.545 us; speedup vs baseline: 6.8640x; 1.2420x over previous
//
#include <hip/hip_runtime.h>
#include <hip/hip_bf16.h>
#include <math.h>

#define N_NODES 50000
#define N_EDGES 800000
#define N_GRAPHS 1024
#define HD 128
#define NLAYERS 5
#define EDGE_IN 41
#define NT 3
#define LN_EPS 1e-5f

typedef unsigned int uint;
typedef unsigned short ushort;
typedef __attribute__((ext_vector_type(8))) short short8;
typedef __attribute__((ext_vector_type(16))) float f32x16;

__device__ __forceinline__ float silu_f(float v) { return v / (1.0f + __expf(-v)); }

// round-to-nearest-even f32 -> bf16 bits
__device__ __forceinline__ ushort f2bf(float f) {
    uint u = __float_as_uint(f);
    u = u + 0x7FFFu + ((u >> 16) & 1u);
    return (ushort)(u >> 16);
}

__device__ __forceinline__ short8 ld16(const ushort* p) {
    union { int4 i; short8 s; } u;
    u.i = *(const int4*)p;
    return u.s;
}

__device__ __forceinline__ f32x16 mfma32(short8 a, short8 b, f32x16 c) {
    return __builtin_amdgcn_mfma_f32_32x32x16_bf16(a, b, c, 0, 0, 0);
}

// ---------------- zero ----------------
__global__ void k_zero(float* __restrict__ p, int n) {
    int i = blockIdx.x * 256 + threadIdx.x;
    if (i < n) p[i] = 0.0f;
}

// ---------------- weight swizzle: B-fragment order, t-major ----------------
// element ((t*16+s)*64+L)*8+j  <-  W[k = s*16 + (L>>5)*8 + j][n = t*32 + (L&31)]
__global__ void k_swz_w1(const float* __restrict__ w1, ushort* __restrict__ w1s) {
    int i = blockIdx.x * 256 + threadIdx.x;            // 5 * 65536
    int l = i >> 16;
    int r = i & 65535;
    int j = r & 7, L = (r >> 3) & 63, s = (r >> 9) & 15, t = (r >> 13) & 7;
    int k = s * 16 + (L >> 5) * 8 + j;
    int n = t * 32 + (L & 31);
    w1s[i] = f2bf(w1[(size_t)l * 65536 + k * 256 + n]);
}
__global__ void k_swz_w2(const float* __restrict__ w2, ushort* __restrict__ w2s) {
    int i = blockIdx.x * 256 + threadIdx.x;            // 5 * 32768
    int l = i >> 15;
    int r = i & 32767;
    int j = r & 7, L = (r >> 3) & 63, s = (r >> 9) & 15, t = (r >> 13) & 3;
    int k = s * 16 + (L >> 5) * 8 + j;
    int n = t * 32 + (L & 31);
    w2s[i] = f2bf(w2[(size_t)l * 32768 + k * 128 + n]);
}

// ---------------- node embed: x = silu(LN(atom @ emb_w + emb_b)) ----------------
__global__ __launch_bounds__(128) void k_node_embed(
    const float* __restrict__ atom, const float* __restrict__ w,
    const float* __restrict__ b, const float* __restrict__ g,
    const float* __restrict__ bet, float* __restrict__ x, ushort* __restrict__ x_bf)
{
    int node = blockIdx.x;
    int h = threadIdx.x;
    float4 a = *(const float4*)(atom + (size_t)node * 4);
    float acc = b[h] + a.x * w[h] + a.y * w[HD + h] + a.z * w[2 * HD + h] + a.w * w[3 * HD + h];
    __shared__ float s1[2], s2[2];
    float sum = acc, sq = acc * acc;
    for (int off = 32; off > 0; off >>= 1) { sum += __shfl_down(sum, off); sq += __shfl_down(sq, off); }
    int wid = h >> 6, lane = h & 63;
    if (lane == 0) { s1[wid] = sum; s2[wid] = sq; }
    __syncthreads();
    float m = (s1[0] + s1[1]) * (1.0f / 128.0f);
    float v = (s2[0] + s2[1]) * (1.0f / 128.0f) - m * m;
    float y = (acc - m) * rsqrtf(v + LN_EPS) * g[h] + bet[h];
    y = silu_f(y);
    x[(size_t)node * HD + h] = y;
    x_bf[(size_t)node * HD + h] = f2bf(y);
}

// ---------------- edge embed -> bf16 ----------------
#define ETILE 32
__global__ __launch_bounds__(128) void k_edge_embed(
    const float* __restrict__ fea, const float* __restrict__ w,
    const float* __restrict__ b, ushort* __restrict__ e_bf)
{
    __shared__ float sf[ETILE][EDGE_IN + 1];
    int e0 = blockIdx.x * ETILE;
    int tid = threadIdx.x;
    for (int i = tid; i < ETILE * EDGE_IN; i += 128) {
        int m = i / EDGE_IN, k = i % EDGE_IN;
        sf[m][k] = fea[(size_t)(e0 + m) * EDGE_IN + k];
    }
    __syncthreads();
    float bb = b[tid];
    float acc[ETILE];
#pragma unroll
    for (int m = 0; m < ETILE; m++) acc[m] = bb;
    for (int k = 0; k < EDGE_IN; k++) {
        float wk = w[k * HD + tid];
#pragma unroll
        for (int m = 0; m < ETILE; m++) acc[m] += sf[m][k] * wk;
    }
#pragma unroll
    for (int m = 0; m < ETILE; m++)
        e_bf[(size_t)(e0 + m) * HD + tid] = f2bf(silu_f(acc[m]));
}

// ---------------- degree / graph counts ----------------
__global__ void k_count(const int* __restrict__ nbr_idx, float* __restrict__ cnt) {
    int i = blockIdx.x * 256 + threadIdx.x;
    if (i < N_EDGES) atomicAdd(&cnt[nbr_idx[2 * i + 1]], 1.0f);
}
__global__ void k_gcount(const int* __restrict__ bm, float* __restrict__ gcnt) {
    int i = blockIdx.x * 256 + threadIdx.x;
    if (i < N_NODES) atomicAdd(&gcnt[bm[i]], 1.0f);
}

// ---------------- fused conv layer (MFMA bf16, 1 wave / 32 edges) ----------------
// GEMM1: m1[32x256] = silu(concat(x[src],e) @ W1 + b1) -> bf16 in LDS
// GEMM2: m2[32x128] = silu(m1 @ W2 + b2), n-pairs serialized (acc 32 regs)
// scatter: atomicAdd(aggr[dst])
#define M1P 264   // pitch: 528 B row stride = 132 words = 4 mod 32 banks -> conflict-free b128
__global__ __launch_bounds__(64, 3) void k_conv_mfma(
    const ushort* __restrict__ x_bf, const ushort* __restrict__ e_bf,
    const int* __restrict__ nbr_idx,
    const ushort* __restrict__ w1s, const float* __restrict__ b1,
    const ushort* __restrict__ w2s, const float* __restrict__ b2,
    float* __restrict__ aggr)
{
    __shared__ __align__(16) ushort sM1[32 * M1P];
    __shared__ int sDst[32];

    int L = threadIdx.x;
    int l31 = L & 31, lhi = L >> 5;
    int e0 = blockIdx.x * 32;

    if (L < 32) sDst[L] = nbr_idx[2 * (e0 + L) + 1];
    int src = nbr_idx[2 * (e0 + l31)];
    const ushort* xb = x_bf + (size_t)src * HD + lhi * 8;
    const ushort* ep = e_bf + (size_t)(e0 + l31) * HD + lhi * 8;
    __syncthreads();

    // ---------- GEMM1 ----------
    for (int c = 0; c < 4; ++c) {
        f32x16 a0, a1;
#pragma unroll
        for (int i = 0; i < 16; ++i) { a0[i] = 0.0f; a1[i] = 0.0f; }
        const ushort* wb = w1s + (2 * c) * 8192 + L * 8;
#pragma unroll
        for (int s = 0; s < 8; ++s) {
            short8 av = ld16(xb + s * 16);
            short8 b0 = ld16(wb + s * 512);
            short8 b1v = ld16(wb + 8192 + s * 512);
            a0 = mfma32(av, b0, a0);
            a1 = mfma32(av, b1v, a1);
        }
#pragma unroll
        for (int s = 0; s < 8; ++s) {
            short8 av = ld16(ep + s * 16);
            short8 b0 = ld16(wb + 4096 + s * 512);
            short8 b1v = ld16(wb + 12288 + s * 512);
            a0 = mfma32(av, b0, a0);
            a1 = mfma32(av, b1v, a1);
        }
        float bv0 = b1[c * 64 + l31];
        float bv1 = b1[c * 64 + 32 + l31];
        ushort* mcol = sM1 + c * 64 + l31;
#pragma unroll
        for (int r = 0; r < 16; ++r) {
            int row = (r & 3) + ((r >> 2) << 3) + (lhi << 2);
            mcol[row * M1P] = f2bf(silu_f(a0[r] + bv0));
            mcol[row * M1P + 32] = f2bf(silu_f(a1[r] + bv1));
        }
    }
    __syncthreads();

    int dstv[16];
#pragma unroll
    for (int r = 0; r < 16; ++r)
        dstv[r] = sDst[(r & 3) + ((r >> 2) << 3) + (lhi << 2)];

    // ---------- GEMM2 (2 n-pairs) ----------
    const ushort* arow = sM1 + l31 * M1P + lhi * 8;
#pragma unroll
    for (int p = 0; p < 2; ++p) {
        f32x16 a0, a1;
#pragma unroll
        for (int i = 0; i < 16; ++i) { a0[i] = 0.0f; a1[i] = 0.0f; }
        const ushort* wb = w2s + (2 * p) * 8192 + L * 8;
#pragma unroll
        for (int ss = 0; ss < 16; ++ss) {
            short8 av = ld16(arow + ss * 16);      // ds_read_b128
            short8 b0 = ld16(wb + ss * 512);
            short8 b1v = ld16(wb + 8192 + ss * 512);
            a0 = mfma32(av, b0, a0);
            a1 = mfma32(av, b1v, a1);
        }
        float bv0 = b2[p * 64 + l31];
        float bv1 = b2[p * 64 + 32 + l31];
#pragma unroll
        for (int r = 0; r < 16; ++r) {
            float* base = aggr + (size_t)dstv[r] * HD + p * 64 + l31;
            atomicAdd(base, silu_f(a0[r] + bv0));
            atomicAdd(base + 32, silu_f(a1[r] + bv1));
        }
    }
}

// ---------------- post: x = LN(x + aggr/cnt); emit bf16 ----------------
__global__ __launch_bounds__(128) void k_post(
    const float* __restrict__ aggr, const float* __restrict__ cnt,
    const float* __restrict__ g, const float* __restrict__ bet,
    float* __restrict__ x, ushort* __restrict__ x_bf)
{
    int node = blockIdx.x;
    int h = threadIdx.x;
    float inv = 1.0f / fmaxf(cnt[node], 1.0f);
    float acc = x[(size_t)node * HD + h] + aggr[(size_t)node * HD + h] * inv;
    __shared__ float s1[2], s2[2];
    float sum = acc, sq = acc * acc;
    for (int off = 32; off > 0; off >>= 1) { sum += __shfl_down(sum, off); sq += __shfl_down(sq, off); }
    int wid = h >> 6, lane = h & 63;
    if (lane == 0) { s1[wid] = sum; s2[wid] = sq; }
    __syncthreads();
    float m = (s1[0] + s1[1]) * (1.0f / 128.0f);
    float v = (s2[0] + s2[1]) * (1.0f / 128.0f) - m * m;
    float y = (acc - m) * rsqrtf(v + LN_EPS) * g[h] + bet[h];
    x[(size_t)node * HD + h] = y;
    x_bf[(size_t)node * HD + h] = f2bf(y);
}

// ---------------- graph pooling ----------------
__global__ __launch_bounds__(128) void k_gaggr(
    const float* __restrict__ x, const int* __restrict__ bm,
    float* __restrict__ crystal)
{
    int node = blockIdx.x;
    int h = threadIdx.x;
    atomicAdd(&crystal[(size_t)bm[node] * HD + h], x[(size_t)node * HD + h]);
}

// ---------------- readout MLP ----------------
__global__ __launch_bounds__(128) void k_readout(
    const float* __restrict__ crystal, const float* __restrict__ gcnt,
    const float* __restrict__ w1, const float* __restrict__ b1,
    const float* __restrict__ w2, const float* __restrict__ b2,
    const float* __restrict__ w3, const float* __restrict__ b3,
    float* __restrict__ out)
{
    int gph = blockIdx.x;
    int t = threadIdx.x;
    __shared__ float sc[HD], sh1[HD], sh2[64];
    float inv = 1.0f / fmaxf(gcnt[gph], 1.0f);
    sc[t] = crystal[(size_t)gph * HD + t] * inv;
    __syncthreads();
    float acc = b1[t];
    for (int k = 0; k < HD; k++) acc += sc[k] * w1[k * HD + t];
    sh1[t] = silu_f(acc);
    __syncthreads();
    if (t < 64) {
        float a2 = b2[t];
        for (int k = 0; k < HD; k++) a2 += sh1[k] * w2[k * 64 + t];
        sh2[t] = silu_f(a2);
    }
    __syncthreads();
    if (t < NT) {
        float a3 = b3[t];
        for (int k = 0; k < 64; k++) a3 += sh2[k] * w3[k * NT + t];
        out[(size_t)gph * NT + t] = a3;
    }
}

extern "C" void kernel_launch(void* const* d_in, const int* in_sizes, int n_in,
                              void* d_out, int out_size, void* d_ws, size_t ws_size,
                              hipStream_t stream)
{
    const float* atom_fea = (const float*)d_in[0];
    const float* nbr_fea  = (const float*)d_in[1];
    const int*   nbr_idx  = (const int*)d_in[2];
    const int*   bm       = (const int*)d_in[3];
    const float* emb_w    = (const float*)d_in[4];
    const float* emb_b    = (const float*)d_in[5];
    const float* emb_ln_g = (const float*)d_in[6];
    const float* emb_ln_b = (const float*)d_in[7];
    const float* edge_w   = (const float*)d_in[8];
    const float* edge_b   = (const float*)d_in[9];
    const float* conv_w1  = (const float*)d_in[10];
    const float* conv_b1  = (const float*)d_in[11];
    const float* conv_w2  = (const float*)d_in[12];
    const float* conv_b2  = (const float*)d_in[13];
    const float* ln_g     = (const float*)d_in[14];
    const float* ln_b     = (const float*)d_in[15];
    const float* out_w1   = (const float*)d_in[16];
    const float* out_b1   = (const float*)d_in[17];
    const float* out_w2   = (const float*)d_in[18];
    const float* out_b2   = (const float*)d_in[19];
    const float* out_w3   = (const float*)d_in[20];
    const float* out_b3   = (const float*)d_in[21];
    float* out = (float*)d_out;

    // ---- workspace layout (256B-aligned regions) ----
    char* base = (char*)d_ws;
    size_t off = 0;
    auto alloc = [&](size_t bytes) -> char* {
        char* p = base + off;
        off = (off + bytes + 255) & ~(size_t)255;
        return p;
    };
    float*  xbuf    = (float*) alloc((size_t)N_NODES * HD * 4);
    float*  aggr    = (float*) alloc((size_t)N_NODES * HD * 4);
    float*  cnt     = (float*) alloc((size_t)N_NODES * 4);
    float*  crystal = (float*) alloc((size_t)N_GRAPHS * HD * 4);
    float*  gcnt    = (float*) alloc((size_t)N_GRAPHS * 4);
    ushort* x_bf    = (ushort*)alloc((size_t)N_NODES * HD * 2);
    ushort* e_bf    = (ushort*)alloc((size_t)N_EDGES * HD * 2);
    ushort* w1s     = (ushort*)alloc((size_t)NLAYERS * 65536 * 2);
    ushort* w2s     = (ushort*)alloc((size_t)NLAYERS * 32768 * 2);

    // weights -> swizzled bf16
    k_swz_w1<<<(NLAYERS * 65536) / 256, 256, 0, stream>>>(conv_w1, w1s);
    k_swz_w2<<<(NLAYERS * 32768) / 256, 256, 0, stream>>>(conv_w2, w2s);

    // zero cnt + crystal + gcnt (contiguous region)
    int zn = N_NODES + N_GRAPHS * HD + N_GRAPHS + 128;
    k_zero<<<(zn + 255) / 256, 256, 0, stream>>>(cnt, zn);

    k_node_embed<<<N_NODES, 128, 0, stream>>>(atom_fea, emb_w, emb_b, emb_ln_g, emb_ln_b, xbuf, x_bf);
    k_edge_embed<<<N_EDGES / ETILE, 128, 0, stream>>>(nbr_fea, edge_w, edge_b, e_bf);
    k_count<<<N_EDGES / 256, 256, 0, stream>>>(nbr_idx, cnt);
    k_gcount<<<(N_NODES + 255) / 256, 256, 0, stream>>>(bm, gcnt);

    for (int l = 0; l < NLAYERS; ++l) {
        k_zero<<<(N_NODES * HD) / 256, 256, 0, stream>>>(aggr, N_NODES * HD);
        k_conv_mfma<<<N_EDGES / 32, 64, 0, stream>>>(
            x_bf, e_bf, nbr_idx,
            w1s + (size_t)l * 65536, conv_b1 + (size_t)l * 256,
            w2s + (size_t)l * 32768, conv_b2 + (size_t)l * 128,
            aggr);
        k_post<<<N_NODES, 128, 0, stream>>>(aggr, cnt, ln_g + (size_t)l * HD, ln_b + (size_t)l * HD, xbuf, x_bf);
    }

    k_gaggr<<<N_NODES, 128, 0, stream>>>(xbuf, bm, crystal);
    k_readout<<<N_GRAPHS, 128, 0, stream>>>(crystal, gcnt, out_w1, out_b1, out_w2, out_b2, out_w3, out_b3, out);
}